// Round 10
// baseline (169.370 us; speedup 1.0000x reference)
//
#include <hip/hip_runtime.h>
#include <math.h>

#define D_MODEL 512
#define NHEAD   8
#define DK      64
#define BATCH   4
#define SEQ     2048
#define MTOT    (BATCH*SEQ)
#define NXELEM  (MTOT*D_MODEL)          // 4,194,304
#define NWELEM  (4*D_MODEL*D_MODEL)     // 1,048,576

typedef _Float16 half8   __attribute__((ext_vector_type(8)));
typedef _Float16 half4_t __attribute__((ext_vector_type(4)));
typedef __fp16   fp16x2  __attribute__((ext_vector_type(2)));  // cvt_pkrtz return type
typedef float    f32x4   __attribute__((ext_vector_type(4)));

#define MFMA32(a,b,c) __builtin_amdgcn_mfma_f32_16x16x32_f16((a),(b),(c),0,0,0)

// wtab scale: dk^-0.5 * log2(e)  (log2e folded so attn uses raw v_exp_f32)
#define WSCALE 0.18033688011117130f

// ---------------------------------------------------------------------------
// Kernel 0: convert x + 4 weights to fp16, and build the wave table
// grid: 5136 x 256 (last 16 blocks do wtab)
// ---------------------------------------------------------------------------
__global__ __launch_bounds__(256) void cvt_kernel(
    const float* __restrict__ x,
    const float* __restrict__ Wq, const float* __restrict__ Wk,
    const float* __restrict__ Wv, const float* __restrict__ Wo,
    const float* __restrict__ wf, const float* __restrict__ wp,
    _Float16* __restrict__ Xh, _Float16* __restrict__ Wh,
    float* __restrict__ wtab)
{
    const int tid = blockIdx.x * 256 + threadIdx.x;
    int idx = tid * 4;
    if (idx < NXELEM + NWELEM) {
        const float* src; _Float16* dst; int off;
        if (idx < NXELEM) { src = x; dst = Xh; off = idx; }
        else {
            int r = idx - NXELEM;
            int sel = r >> 18;                 // 512*512 = 2^18
            off = r & ((1 << 18) - 1);
            src = (sel == 0) ? Wq : (sel == 1) ? Wk : (sel == 2) ? Wv : Wo;
            dst = Wh + ((size_t)sel << 18);
        }
        float4 v = *(const float4*)(src + off);
        half4_t h;
        h[0] = (_Float16)v.x; h[1] = (_Float16)v.y;
        h[2] = (_Float16)v.z; h[3] = (_Float16)v.w;
        *(half4_t*)(dst + off) = h;
    } else {
        int widx = idx - (NXELEM + NWELEM);    // 0 .. 16380, 4-aligned
        const int h = widx >> 11;
        const int pos0 = widx & 2047;
        const float f  = 6.28318530717958647692f * wf[h];
        const float ph = wp[h];
        float4 o;
        o.x = WSCALE * cosf(fmaf(f, (float)(pos0 + 0), ph));
        o.y = WSCALE * cosf(fmaf(f, (float)(pos0 + 1), ph));
        o.z = WSCALE * cosf(fmaf(f, (float)(pos0 + 2), ph));
        o.w = WSCALE * cosf(fmaf(f, (float)(pos0 + 3), ph));
        *(float4*)(wtab + widx) = o;
    }
}

// ---------------------------------------------------------------------------
// Kernel 1: fused QKV projection, fp16 MFMA (unchanged from round 9).
// grid: (8, 64), block 256
// ---------------------------------------------------------------------------
__global__ __launch_bounds__(256) void qkv_mfma_kernel(
    const _Float16* __restrict__ Xh, const _Float16* __restrict__ Wh,
    const float* __restrict__ wtab,
    _Float16* __restrict__ Qh, _Float16* __restrict__ Kh,
    _Float16* __restrict__ Vth)
{
    __shared__ _Float16 As[128][72];   // [m][k], pad 8          18.4 KB
    __shared__ _Float16 Bs[192][72];   // [which*64 + n][k]      27.6 KB

    const int t  = threadIdx.x;
    const int h  = blockIdx.x;
    const int m0 = blockIdx.y * 128;

    const int w = t >> 6, lane = t & 63, ln = lane & 15, quad = lane >> 4;
    const int ar = t >> 1, ac = (t & 1) * 32;
    const int br = t >> 2, bc = (t & 3) * 16;

    const _Float16* ag  = Xh + (size_t)(m0 + ar) * 512 + ac;
    const _Float16* bg0 = Wh + (size_t)(h * 64 + br) * 512 + bc;
    const _Float16* bg1 = bg0 + (1 << 18);
    const _Float16* bg2 = bg0 + (2 << 18);

    const f32x4 kZero = {0.f, 0.f, 0.f, 0.f};
    f32x4 acc[3][2][4];
    #pragma unroll
    for (int c = 0; c < 3; ++c)
        #pragma unroll
        for (int i = 0; i < 2; ++i)
            #pragma unroll
            for (int j = 0; j < 4; ++j) acc[c][i][j] = kZero;

    for (int k0 = 0; k0 < 512; k0 += 64) {
        half8 av[4], bv[6];
        #pragma unroll
        for (int i = 0; i < 4; ++i) av[i] = *(const half8*)(ag + k0 + i * 8);
        bv[0] = *(const half8*)(bg0 + k0);
        bv[1] = *(const half8*)(bg0 + k0 + 8);
        bv[2] = *(const half8*)(bg1 + k0);
        bv[3] = *(const half8*)(bg1 + k0 + 8);
        bv[4] = *(const half8*)(bg2 + k0);
        bv[5] = *(const half8*)(bg2 + k0 + 8);
        __syncthreads();
        #pragma unroll
        for (int i = 0; i < 4; ++i) *(half8*)&As[ar][ac + i * 8] = av[i];
        #pragma unroll
        for (int c = 0; c < 3; ++c) {
            *(half8*)&Bs[c * 64 + br][bc]     = bv[2 * c];
            *(half8*)&Bs[c * 64 + br][bc + 8] = bv[2 * c + 1];
        }
        __syncthreads();

        #pragma unroll
        for (int ks = 0; ks < 2; ++ks) {
            half8 af[2];
            #pragma unroll
            for (int mt = 0; mt < 2; ++mt)
                af[mt] = *(const half8*)&As[w * 32 + mt * 16 + ln][ks * 32 + quad * 8];
            #pragma unroll
            for (int c = 0; c < 3; ++c) {
                half8 bf[4];
                #pragma unroll
                for (int nt = 0; nt < 4; ++nt)
                    bf[nt] = *(const half8*)&Bs[c * 64 + nt * 16 + ln][ks * 32 + quad * 8];
                #pragma unroll
                for (int mt = 0; mt < 2; ++mt)
                    #pragma unroll
                    for (int nt = 0; nt < 4; ++nt)
                        acc[c][mt][nt] = MFMA32(af[mt], bf[nt], acc[c][mt][nt]);
            }
        }
    }

    const int b  = m0 >> 11;
    const int l0 = m0 & 2047;
    const float* wt = wtab + h * SEQ;

    #pragma unroll
    for (int which = 0; which < 2; ++which) {
        _Float16* dst = (which == 0 ? Qh : Kh) + (size_t)(b * NHEAD + h) * SEQ * DK;
        __syncthreads();
        _Float16* Ql = &As[0][0];
        #pragma unroll
        for (int mt = 0; mt < 2; ++mt)
            #pragma unroll
            for (int r = 0; r < 4; ++r) {
                const int lr = w * 32 + mt * 16 + quad * 4 + r;
                const float wv = (which == 1) ? wt[l0 + lr] : 1.0f;
                #pragma unroll
                for (int nt = 0; nt < 4; ++nt)
                    Ql[lr * 72 + nt * 16 + ln] = (_Float16)(acc[which][mt][nt][r] * wv);
            }
        __syncthreads();
        #pragma unroll
        for (int rr = 0; rr < 4; ++rr) {
            const int row = rr * 32 + (t >> 3);
            half8 v = *(const half8*)&Ql[row * 72 + (t & 7) * 8];
            *(half8*)(dst + (size_t)(l0 + row) * DK + (t & 7) * 8) = v;
        }
    }

    __syncthreads();
    _Float16* Vl = &As[0][0];
    #pragma unroll
    for (int nt = 0; nt < 4; ++nt) {
        half8 hv;
        #pragma unroll
        for (int mt = 0; mt < 2; ++mt)
            #pragma unroll
            for (int r = 0; r < 4; ++r)
                hv[mt * 4 + r] = (_Float16)acc[2][mt][nt][r];
        const int d = nt * 16 + ln;
        *(half8*)&Vl[d * 136 + w * 32 + quad * 8] = hv;
    }
    __syncthreads();
    _Float16* dst = Vth + (size_t)(b * NHEAD + h) * DK * SEQ;
    #pragma unroll
    for (int rr = 0; rr < 4; ++rr) {
        const int d = rr * 16 + (t >> 4);
        half8 v = *(const half8*)&Vl[d * 136 + (t & 15) * 8];
        *(half8*)(dst + (size_t)d * SEQ + l0 + (t & 15) * 8) = v;
    }
}

// ---------------------------------------------------------------------------
// Kernel 2: flash attention, fp16 MFMA, max-free softmax, split-K in block.
//   NEW: 4 waves/block (2 q-row-groups x 2 key-halves), 64 q-rows PER WAVE
//   (u=4) -> MFMA:LDS-read ratio 4:1 (was 2:1).  32-key tiles, 32 steps/half,
//   double-buffered, two barriers/step (race-proof), register prefetch.
//   LDS 38.9 KB -> up to 4 blocks/CU.
// grid: 512 linear, block 256
// ---------------------------------------------------------------------------
// LDS layout (halves of _Float16):
//   buf b (0,1), key-half h (0,1):  K at b*9728 + h*4864   [32][72]
//                                   V at K + 2304          [64][40]
//   Q staged at offset 9728 (buf1 region), [128][64] unpadded, dead after
//   fragment extraction (kt=0's write window overwrites it - after barrier).
#define KOFF(h,b) ((b) * 9728 + (h) * 4864)
#define VOFF(h,b) (KOFF(h,b) + 2304)
#define QOFF      9728

__global__ __launch_bounds__(256) void attn_mfma_kernel(
    const _Float16* __restrict__ Qh, const _Float16* __restrict__ Kwh,
    const _Float16* __restrict__ Vth, _Float16* __restrict__ AOh)
{
    __shared__ _Float16 SMEM[19456];   // 38,912 B

    const int bx = blockIdx.x;           // 0..511
    const int g8 = bx & 7;               // XCD (dispatch round-robin)
    const int s  = bx >> 3;              // 0..63
    const int bh = g8 * 4 + (s >> 4);    // XCD g owns bh 4g..4g+3
    const int q0 = (s & 15) * 128;
    const int b = bh >> 3, h = bh & 7;

    const int t = threadIdx.x;           // 0..255
    const int w = t >> 6;                // 0..3
    const int wg = w & 1;                // q-row group (64 rows each)
    const int ch = w >> 1;               // key half (also staging half: ch==t>>7)
    const int lane = t & 63, ln = lane & 15, quad = lane >> 4;

    const _Float16* Qg = Qh + ((size_t)bh * SEQ + q0) * DK;
    const _Float16* Kg = Kwh + (size_t)bh * SEQ * DK;
    const _Float16* Vg = Vth + (size_t)bh * DK * SEQ;
    const int kbase = (t >> 7) * 1024;   // staging half's key base

    const int tl  = t & 127;
    const int skr = tl >> 2, skc = (tl & 3) * 16;   // K staging: 32 rows x 64
    const int svr = tl >> 1, svc = (tl & 1) * 16;   // V staging: 64 rows x 32

    // prologue: stage Q ([128][64] at QOFF) and K0,V0 (buf0, both halves)
    {
        const int qr = t >> 1, qc = (t & 1) * 32;
        const _Float16* qp = Qg + (size_t)qr * DK + qc;
        half8 q0v = *(const half8*)(qp);
        half8 q1v = *(const half8*)(qp + 8);
        half8 q2v = *(const half8*)(qp + 16);
        half8 q3v = *(const half8*)(qp + 24);
        const _Float16* kp = Kg + (size_t)(kbase + skr) * DK + skc;
        const _Float16* vp = Vg + (size_t)svr * SEQ + kbase + svc;
        half8 kv0 = *(const half8*)(kp);
        half8 kv1 = *(const half8*)(kp + 8);
        half8 vv0 = *(const half8*)(vp);
        half8 vv1 = *(const half8*)(vp + 8);
        _Float16* qd = &SMEM[QOFF + qr * 64 + qc];
        *(half8*)(qd)      = q0v;
        *(half8*)(qd + 8)  = q1v;
        *(half8*)(qd + 16) = q2v;
        *(half8*)(qd + 24) = q3v;
        _Float16* kd = &SMEM[KOFF(t >> 7, 0) + skr * 72 + skc];
        _Float16* vd = &SMEM[VOFF(t >> 7, 0) + svr * 40 + svc];
        *(half8*)(kd)     = kv0;
        *(half8*)(kd + 8) = kv1;
        *(half8*)(vd)     = vv0;
        *(half8*)(vd + 8) = vv1;
    }
    __syncthreads();

    // extract Q fragments: wave covers q rows wg*64 .. wg*64+63 (u=0..3)
    half8 qf[4][2];
    #pragma unroll
    for (int u = 0; u < 4; ++u) {
        const _Float16* qsrc = &SMEM[QOFF + (wg * 64 + u * 16 + ln) * 64];
        qf[u][0] = *(const half8*)(qsrc + quad * 8);
        qf[u][1] = *(const half8*)(qsrc + 32 + quad * 8);
    }
    __syncthreads();   // all waves extracted before kt=0 write window (buf1=Q)

    const f32x4 kZero = {0.f, 0.f, 0.f, 0.f};
    f32x4 o[4][4];         // o[u][nt][r]: q row wg*64+u*16+quad*4+r, d nt*16+ln
    #pragma unroll
    for (int u = 0; u < 4; ++u)
        #pragma unroll
        for (int nt = 0; nt < 4; ++nt) o[u][nt] = kZero;
    float l_acc[4] = {0.f, 0.f, 0.f, 0.f};

    for (int kt = 0; kt < 32; ++kt) {    // 32 tiles of 32 keys per half
        const int cur = kt & 1;

        half8 pk0, pk1, pv0, pv1;
        const bool more = (kt + 1 < 32);
        if (more) {
            const _Float16* kp = Kg + (size_t)(kbase + (kt + 1) * 32 + skr) * DK + skc;
            const _Float16* vp = Vg + (size_t)svr * SEQ + kbase + (kt + 1) * 32 + svc;
            pk0 = *(const half8*)(kp);
            pk1 = *(const half8*)(kp + 8);
            pv0 = *(const half8*)(vp);
            pv1 = *(const half8*)(vp + 8);
        }

        const _Float16* Ks = &SMEM[KOFF(ch, cur)];   // [32][72]
        const _Float16* Vs = &SMEM[VOFF(ch, cur)];   // [64][40]

        half8 ka0 = *(const half8*)&Ks[(ln)      * 72 + quad * 8];
        half8 ka1 = *(const half8*)&Ks[(ln)      * 72 + 32 + quad * 8];
        half8 kb0 = *(const half8*)&Ks[(16 + ln) * 72 + quad * 8];
        half8 kb1 = *(const half8*)&Ks[(16 + ln) * 72 + 32 + quad * 8];
        half8 vf[4];
        #pragma unroll
        for (int nt = 0; nt < 4; ++nt)
            vf[nt] = *(const half8*)&Vs[(nt * 16 + ln) * 40 + quad * 8];

        #pragma unroll
        for (int u = 0; u < 4; ++u) {
            f32x4 s0 = MFMA32(ka0, qf[u][0], kZero);
            f32x4 s1 = MFMA32(kb0, qf[u][0], kZero);
            s0 = MFMA32(ka1, qf[u][1], s0);
            s1 = MFMA32(kb1, qf[u][1], s1);

            const float e00 = __builtin_amdgcn_exp2f(s0[0]);
            const float e01 = __builtin_amdgcn_exp2f(s0[1]);
            const float e02 = __builtin_amdgcn_exp2f(s0[2]);
            const float e03 = __builtin_amdgcn_exp2f(s0[3]);
            const float e10 = __builtin_amdgcn_exp2f(s1[0]);
            const float e11 = __builtin_amdgcn_exp2f(s1[1]);
            const float e12 = __builtin_amdgcn_exp2f(s1[2]);
            const float e13 = __builtin_amdgcn_exp2f(s1[3]);
            union { half8 v; fp16x2 h2[4]; } pu;
            pu.h2[0] = __builtin_amdgcn_cvt_pkrtz(e00, e01);
            pu.h2[1] = __builtin_amdgcn_cvt_pkrtz(e02, e03);
            pu.h2[2] = __builtin_amdgcn_cvt_pkrtz(e10, e11);
            pu.h2[3] = __builtin_amdgcn_cvt_pkrtz(e12, e13);
            l_acc[u] += ((e00 + e01) + (e02 + e03)) + ((e10 + e11) + (e12 + e13));

            #pragma unroll
            for (int nt = 0; nt < 4; ++nt)
                o[u][nt] = MFMA32(pu.v, vf[nt], o[u][nt]);
        }

        __syncthreads();                 // all reads of both buffers done
        if (more) {
            _Float16* kd = &SMEM[KOFF(t >> 7, cur ^ 1) + skr * 72 + skc];
            _Float16* vd = &SMEM[VOFF(t >> 7, cur ^ 1) + svr * 40 + svc];
            *(half8*)(kd)     = pk0;
            *(half8*)(kd + 8) = pk1;
            *(half8*)(vd)     = pv0;
            *(half8*)(vd + 8) = pv1;
        }
        __syncthreads();                 // writes visible before next reads
    }

    // ---- combine key-halves (exact: o,l are pure sums) ----
    float* OP = (float*)&SMEM[0];        // 68 slots x 129 floats = 35.1 KB
    const int idx = wg * 64 + lane;      // 0..127
    if (ch == 1) {
        #pragma unroll
        for (int u = 0; u < 4; ++u) {
            #pragma unroll
            for (int nt = 0; nt < 4; ++nt)
                #pragma unroll
                for (int r = 0; r < 4; ++r)
                    OP[((u * 4 + nt) * 4 + r) * 129 + idx] = o[u][nt][r];
            OP[(64 + u) * 129 + idx] = l_acc[u];
        }
    }
    __syncthreads();
    if (ch == 0) {
        #pragma unroll
        for (int u = 0; u < 4; ++u) {
            #pragma unroll
            for (int nt = 0; nt < 4; ++nt)
                #pragma unroll
                for (int r = 0; r < 4; ++r)
                    o[u][nt][r] += OP[((u * 4 + nt) * 4 + r) * 129 + idx];
            l_acc[u] += OP[(64 + u) * 129 + idx];
        }

        #pragma unroll
        for (int u = 0; u < 4; ++u) {
            l_acc[u] += __shfl_xor(l_acc[u], 16);
            l_acc[u] += __shfl_xor(l_acc[u], 32);
        }

        #pragma unroll
        for (int u = 0; u < 4; ++u)
            #pragma unroll
            for (int r = 0; r < 4; ++r) {
                const float lr  = __shfl(l_acc[u], quad * 4 + r, 16);
                const float inv = 1.0f / lr;
                const int lq = q0 + wg * 64 + u * 16 + quad * 4 + r;
                const size_t base = ((size_t)b * SEQ + lq) * D_MODEL + h * DK;
                #pragma unroll
                for (int nt = 0; nt < 4; ++nt)
                    AOh[base + nt * 16 + ln] = (_Float16)(o[u][nt][r] * inv);
            }
    }
}

// ---------------------------------------------------------------------------
// Kernel 3: output projection, fp16 MFMA (unchanged from round 9).
// grid: (8, 64), block 256
// ---------------------------------------------------------------------------
__global__ __launch_bounds__(256) void out_mfma_kernel(
    const _Float16* __restrict__ AOh, const _Float16* __restrict__ Woh,
    float* __restrict__ out)
{
    __shared__ _Float16 As[128][72];
    __shared__ _Float16 Bs[64][72];

    const int t  = threadIdx.x;
    const int n0 = blockIdx.x * 64;
    const int m0 = blockIdx.y * 128;

    const int w = t >> 6, lane = t & 63, ln = lane & 15, quad = lane >> 4;
    const int ar = t >> 1, ac = (t & 1) * 32;
    const int br = t >> 2, bc = (t & 3) * 16;

    const _Float16* ag = AOh + (size_t)(m0 + ar) * 512 + ac;
    const _Float16* bg = Woh + (size_t)(n0 + br) * 512 + bc;

    const f32x4 kZero = {0.f, 0.f, 0.f, 0.f};
    f32x4 acc[2][4];
    #pragma unroll
    for (int i = 0; i < 2; ++i)
        #pragma unroll
        for (int j = 0; j < 4; ++j) acc[i][j] = kZero;

    for (int k0 = 0; k0 < 512; k0 += 64) {
        half8 av[4], bv[2];
        #pragma unroll
        for (int i = 0; i < 4; ++i) av[i] = *(const half8*)(ag + k0 + i * 8);
        #pragma unroll
        for (int i = 0; i < 2; ++i) bv[i] = *(const half8*)(bg + k0 + i * 8);
        __syncthreads();
        #pragma unroll
        for (int i = 0; i < 4; ++i) *(half8*)&As[ar][ac + i * 8] = av[i];
        #pragma unroll
        for (int i = 0; i < 2; ++i) *(half8*)&Bs[br][bc + i * 8] = bv[i];
        __syncthreads();

        #pragma unroll
        for (int ks = 0; ks < 2; ++ks) {
            half8 af[2], bf[4];
            #pragma unroll
            for (int mt = 0; mt < 2; ++mt)
                af[mt] = *(const half8*)&As[w * 32 + mt * 16 + ln][ks * 32 + quad * 8];
            #pragma unroll
            for (int nt = 0; nt < 4; ++nt)
                bf[nt] = *(const half8*)&Bs[nt * 16 + ln][ks * 32 + quad * 8];
            #pragma unroll
            for (int mt = 0; mt < 2; ++mt)
                #pragma unroll
                for (int nt = 0; nt < 4; ++nt)
                    acc[mt][nt] = MFMA32(af[mt], bf[nt], acc[mt][nt]);
        }
    }

    float* Os = (float*)&As[0][0];     // [64][66] floats = 16.9KB
    #pragma unroll
    for (int pass = 0; pass < 2; ++pass) {
        __syncthreads();
        if ((w >> 1) == pass) {
            const int rbase = (w & 1) * 32;
            #pragma unroll
            for (int mt = 0; mt < 2; ++mt)
                #pragma unroll
                for (int r = 0; r < 4; ++r) {
                    const int row = rbase + mt * 16 + quad * 4 + r;
                    #pragma unroll
                    for (int nt = 0; nt < 4; ++nt)
                        Os[row * 66 + nt * 16 + ln] = acc[mt][nt][r];
                }
        }
        __syncthreads();
        #pragma unroll
        for (int rr = 0; rr < 4; ++rr) {
            const int row = rr * 16 + (t >> 4);
            float4 v = *(const float4*)&Os[row * 66 + (t & 15) * 4];
            *(float4*)(out + (size_t)(m0 + pass * 64 + row) * 512 + n0 + (t & 15) * 4) = v;
        }
    }
}

// ---------------------------------------------------------------------------
extern "C" void kernel_launch(void* const* d_in, const int* in_sizes, int n_in,
                              void* d_out, int out_size, void* d_ws, size_t ws_size,
                              hipStream_t stream)
{
    (void)in_sizes; (void)n_in; (void)out_size; (void)ws_size;
    const float* x  = (const float*)d_in[0];
    const float* Wq = (const float*)d_in[1];
    const float* Wk = (const float*)d_in[2];
    const float* Wv = (const float*)d_in[3];
    const float* Wo = (const float*)d_in[4];
    const float* wf = (const float*)d_in[5];
    const float* wp = (const float*)d_in[6];
    float* out = (float*)d_out;

    const size_t NX = (size_t)MTOT * D_MODEL;        // 4,194,304
    _Float16* Xh  = (_Float16*)d_ws;
    _Float16* Wh  = Xh + NX;                          // 4 x 262144
    _Float16* Qh  = Wh + 4 * 262144;
    _Float16* Kh  = Qh + NX;                          // pre-scaled K'
    _Float16* Vth = Kh + NX;                          // transposed+swizzled V
    _Float16* AOh = Vth + NX;
    float*    wtab = (float*)(AOh + NX);              // 8 x 2048 fp32

    cvt_kernel<<<5136, 256, 0, stream>>>(x, Wq, Wk, Wv, Wo, wf, wp, Xh, Wh, wtab);

    dim3 g1(8, 64);
    qkv_mfma_kernel<<<g1, 256, 0, stream>>>(Xh, Wh, wtab, Qh, Kh, Vth);

    attn_mfma_kernel<<<512, 256, 0, stream>>>(Qh, Kh, Vth, AOh);

    dim3 g3(8, 64);
    out_mfma_kernel<<<g3, 256, 0, stream>>>(AOh, Wh + 3 * 262144, out);
}